// Round 7
// baseline (469.419 us; speedup 1.0000x reference)
//
#include <hip/hip_runtime.h>
#include <hip/hip_cooperative_groups.h>

namespace cg = cooperative_groups;

#define T_LEN 4096
#define H 16
#define N 16
#define D 64
#define NC 128
#define CL (T_LEN / NC)      // 32
#define WPB 8                // waves per block (512 threads)
#define NBLK (NC * H / WPB)  // 256 blocks -- one per CU, co-residency safe

// One fused cooperative kernel.
//   Phase A: wave g=(c,h): local scan from 0 with fused C-projection;
//            keeps out_local[CL] in VGPRs. Writes L[c][h][n][d], P[h][c].
//   Phase B: wave 0 of each of the 256 blocks (1 wave/CU): serial
//            cross-chunk combine, 64-deep prefetch; overwrites L with
//            chunk ENTRY states; writes next_carry.
//   Phase C: out[t] = out_local[t] + pa(t) * (C_t . entry)  (linearity).
//            ã recomputed from dt/mask (L2-resident s_loads) - no aa[].
//
// __launch_bounds__(512, 1): min ONE 512-thread block/CU -> 2 waves/SIMD
// -> VGPR cap 256 (not 128). Rounds 4/6 spilled xw[] to scratch at cap 128
// (FETCH 288 MB vs 42 MB ideal); round 5's (256,1) allowed 512 VGPR ->
// cooperative co-residency failed. This is the only configuration that
// both co-resides 256 blocks and keeps the register file large enough.
__global__ __launch_bounds__(WPB * 64, 1)
void mamba_fused(const float* __restrict__ x, const float* __restrict__ dt,
                 const float* __restrict__ B, const float* __restrict__ C,
                 const float* __restrict__ mask, const float* __restrict__ ic,
                 const float* __restrict__ ld, const float* __restrict__ sw,
                 float* __restrict__ out, float* __restrict__ Lbuf,
                 float* __restrict__ Pbuf) {
    const int tid = threadIdx.x;
    const int wv = tid >> 6, d = tid & 63;
    const int g = blockIdx.x * WPB + wv;   // (chunk, head) pair index
    const int c = g >> 4, h = g & 15;
    const int t0 = c * CL;
    const float rate = -__expf(ld[h]);

    __shared__ float Bs[WPB][CL * N];      // dt-scaled B panel, 16 KB
    __shared__ float Cs[WPB][CL * N];      // C panel, 16 KB

    // ---- stage panels (B pre-scaled by dt), coalesced float4 ----
    {
        const float4* Bg = (const float4*)B;
        const float4* Cg = (const float4*)C;
        float4* Bsv = (float4*)Bs[wv];
        float4* Csv = (float4*)Cs[wv];
#pragma unroll
        for (int i = 0; i < 2; ++i) {
            const int j = i * 64 + d;
            const int row = j >> 2, off = j & 3;
            const float dtv = dt[(t0 + row) * H + h];
            float4 bv = Bg[((t0 + row) * H + h) * (N / 4) + off];
            bv.x *= dtv; bv.y *= dtv; bv.z *= dtv; bv.w *= dtv;
            Bsv[j] = bv;
            Csv[j] = Cg[((t0 + row) * H + h) * (N / 4) + off];
        }
    }

    // ---- x tile in registers (becomes out_local) ----
    float xw[CL];
#pragma unroll
    for (int ss = 0; ss < CL; ++ss)
        xw[ss] = x[((t0 + ss) * H + h) * D + d];
    __syncthreads();

    // ---- Phase A: local scan + fused C-projection ----
    float s[N];
#pragma unroll
    for (int n = 0; n < N; ++n) s[n] = 0.f;
    const float swv = sw[h * D + d];
    float P = 1.f;
#pragma unroll
    for (int ss = 0; ss < CL; ++ss) {
        const float dtv = dt[(t0 + ss) * H + h];   // wave-uniform s_load
        const float mv  = mask[t0 + ss];
        const float a   = (1.f - mv) * __expf(dtv * rate);
        const float xv  = xw[ss];
        P *= a;
        float acc = swv * xv;
        const float4* Br4 = (const float4*)(Bs[wv] + ss * N);
        const float4* Cr4 = (const float4*)(Cs[wv] + ss * N);
#pragma unroll
        for (int q = 0; q < 4; ++q) {               // ds_read_b128 broadcasts
            const float4 bv = Br4[q];
            const float4 cv = Cr4[q];
            s[4*q+0] = a * s[4*q+0] + bv.x * xv;  acc += cv.x * s[4*q+0];
            s[4*q+1] = a * s[4*q+1] + bv.y * xv;  acc += cv.y * s[4*q+1];
            s[4*q+2] = a * s[4*q+2] + bv.z * xv;  acc += cv.z * s[4*q+2];
            s[4*q+3] = a * s[4*q+3] + bv.w * xv;  acc += cv.w * s[4*q+3];
        }
        xw[ss] = acc;                               // out_local
    }
    {
        float* Lp = Lbuf + ((c * H + h) * N) * D + d;
#pragma unroll
        for (int n = 0; n < N; ++n) Lp[n * D] = s[n];
        if (d == 0) Pbuf[h * NC + c] = P;
    }

    cg::this_grid().sync();

    // ---- Phase B: wave 0 of each block -> 16384 lanes, 1 wave/CU ----
    if (wv == 0) {
        const int idx = blockIdx.x * 64 + d;        // h*1024 + n*64 + d
        const int hh = idx >> 10;                   // wave-uniform
        float carry = ic[idx];
#pragma unroll
        for (int r = 0; r < NC / 64; ++r) {
            float l[64];
#pragma unroll
            for (int k = 0; k < 64; ++k)
                l[k] = Lbuf[(r * 64 + k) * (H * N * D) + idx];
#pragma unroll
            for (int k = 0; k < 64; ++k) {
                const float p = Pbuf[hh * NC + r * 64 + k];  // s_load
                Lbuf[(r * 64 + k) * (H * N * D) + idx] = carry;  // entry
                carry = p * carry + l[k];
            }
        }
        out[idx] = carry;                           // next_carry
    }

    cg::this_grid().sync();

    // ---- Phase C: entry correction, ã recomputed (no aa[] array) ----
    float E[N];
    {
        const float* Ep = Lbuf + ((c * H + h) * N) * D + d;
#pragma unroll
        for (int n = 0; n < N; ++n) E[n] = Ep[n * D];
    }
    float pa = 1.f;
    float* outp = out + H * N * D;
#pragma unroll
    for (int ss = 0; ss < CL; ++ss) {
        const float dtv = dt[(t0 + ss) * H + h];    // L2-resident s_load
        const float mv  = mask[t0 + ss];
        pa *= (1.f - mv) * __expf(dtv * rate);
        const float4* Cr4 = (const float4*)(Cs[wv] + ss * N);
        float corr = 0.f;
#pragma unroll
        for (int q = 0; q < 4; ++q) {
            const float4 cv = Cr4[q];
            corr += cv.x * E[4*q+0] + cv.y * E[4*q+1]
                  + cv.z * E[4*q+2] + cv.w * E[4*q+3];
        }
        outp[((t0 + ss) * H + h) * D + d] = xw[ss] + pa * corr;
    }
}

extern "C" void kernel_launch(void* const* d_in, const int* in_sizes, int n_in,
                              void* d_out, int out_size, void* d_ws, size_t ws_size,
                              hipStream_t stream) {
    const float* x    = (const float*)d_in[0];
    const float* dt   = (const float*)d_in[1];
    const float* B    = (const float*)d_in[2];
    const float* C    = (const float*)d_in[3];
    const float* mask = (const float*)d_in[4];
    const float* ic   = (const float*)d_in[5];
    const float* ld   = (const float*)d_in[6];
    const float* sw   = (const float*)d_in[7];
    float* out = (float*)d_out;

    float* Lbuf = (float*)d_ws;                      // NC*H*N*D floats
    float* Pbuf = Lbuf + (size_t)NC * H * N * D;     // H*NC floats

    void* args[] = {(void*)&x, (void*)&dt, (void*)&B, (void*)&C,
                    (void*)&mask, (void*)&ic, (void*)&ld, (void*)&sw,
                    (void*)&out, (void*)&Lbuf, (void*)&Pbuf};
    hipLaunchCooperativeKernel((void*)mamba_fused, dim3(NBLK), dim3(WPB * 64),
                               args, 0, stream);
}

// Round 8
// 115.150 us; speedup vs baseline: 4.0766x; 4.0766x over previous
//
#include <hip/hip_runtime.h>
#include <hip/hip_cooperative_groups.h>

namespace cg = cooperative_groups;

#define T_LEN 4096
#define H 16
#define N 16
#define D 64
#define NC 128
#define CL (T_LEN / NC)      // 32
#define WPB 8                // waves per block (512 threads)
#define NBLK (NC * H / WPB)  // 256 blocks -- one per CU, co-residency safe

// Fused cooperative kernel, round 8: out_local lives in LDS (Xs), not VGPRs.
// Rounds 4/6/7 proved the compiler pins this kernel at 128 VGPRs; xw[32] in
// registers spilled to scratch (288 MB FETCH / 567 MB WRITE vs ~76 MB ideal).
// LDS budget: Bs 16K + Cs 16K + Xs 64K = 96 KB -> 1 block/CU, 256 blocks.
//   Phase A: wave g=(c,h): local scan from 0 with fused C-projection;
//            x-tile staged in Xs, overwritten in place with out_local.
//            Writes L[c][h][n][d], P[h][c].
//   Phase B: wave 0 per block (16384 lanes, 1 wave/CU): serial cross-chunk
//            combine, 64-deep prefetch; overwrites L with chunk ENTRY
//            states; writes next_carry.
//   Phase C: out[t] = out_local[t] + pa(t) * (C_t . entry)   (linearity).
//            ã recomputed from dt/mask (L2-resident); C-panel still in LDS.
__global__ __launch_bounds__(WPB * 64, 1)
void mamba_fused(const float* __restrict__ x, const float* __restrict__ dt,
                 const float* __restrict__ B, const float* __restrict__ C,
                 const float* __restrict__ mask, const float* __restrict__ ic,
                 const float* __restrict__ ld, const float* __restrict__ sw,
                 float* __restrict__ out, float* __restrict__ Lbuf,
                 float* __restrict__ Pbuf) {
    const int tid = threadIdx.x;
    const int wv = tid >> 6, d = tid & 63;
    const int g = blockIdx.x * WPB + wv;   // (chunk, head) pair index
    const int c = g >> 4, h = g & 15;
    const int t0 = c * CL;
    const float rate = -__expf(ld[h]);

    __shared__ float Bs[WPB][CL * N];      // dt-scaled B panel, 16 KB
    __shared__ float Cs[WPB][CL * N];      // C panel, 16 KB
    __shared__ float Xs[WPB][CL][D];       // x tile -> out_local, 64 KB

    // ---- stage panels (B pre-scaled by dt), coalesced float4 ----
    {
        const float4* Bg = (const float4*)B;
        const float4* Cg = (const float4*)C;
        float4* Bsv = (float4*)Bs[wv];
        float4* Csv = (float4*)Cs[wv];
#pragma unroll
        for (int i = 0; i < 2; ++i) {
            const int j = i * 64 + d;
            const int row = j >> 2, off = j & 3;
            const float dtv = dt[(t0 + row) * H + h];
            float4 bv = Bg[((t0 + row) * H + h) * (N / 4) + off];
            bv.x *= dtv; bv.y *= dtv; bv.z *= dtv; bv.w *= dtv;
            Bsv[j] = bv;
            Csv[j] = Cg[((t0 + row) * H + h) * (N / 4) + off];
        }
    }

    // ---- x tile into LDS (coalesced global, conflict-free ds_write) ----
#pragma unroll
    for (int ss = 0; ss < CL; ++ss)
        Xs[wv][ss][d] = x[((t0 + ss) * H + h) * D + d];
    __syncthreads();   // (stripes are per-wave; kept for safety, negligible)

    // ---- Phase A: local scan + fused C-projection; Xs <- out_local ----
    float s[N];
#pragma unroll
    for (int n = 0; n < N; ++n) s[n] = 0.f;
    const float swv = sw[h * D + d];
    float P = 1.f;
#pragma unroll
    for (int ss = 0; ss < CL; ++ss) {
        const float dtv = dt[(t0 + ss) * H + h];   // wave-uniform s_load
        const float mv  = mask[t0 + ss];
        const float a   = (1.f - mv) * __expf(dtv * rate);
        const float xv  = Xs[wv][ss][d];
        P *= a;
        float acc = swv * xv;
        const float4* Br4 = (const float4*)(Bs[wv] + ss * N);
        const float4* Cr4 = (const float4*)(Cs[wv] + ss * N);
#pragma unroll
        for (int q = 0; q < 4; ++q) {               // ds_read_b128 broadcasts
            const float4 bv = Br4[q];
            const float4 cv = Cr4[q];
            s[4*q+0] = a * s[4*q+0] + bv.x * xv;  acc += cv.x * s[4*q+0];
            s[4*q+1] = a * s[4*q+1] + bv.y * xv;  acc += cv.y * s[4*q+1];
            s[4*q+2] = a * s[4*q+2] + bv.z * xv;  acc += cv.z * s[4*q+2];
            s[4*q+3] = a * s[4*q+3] + bv.w * xv;  acc += cv.w * s[4*q+3];
        }
        Xs[wv][ss][d] = acc;                        // out_local
    }
    {
        float* Lp = Lbuf + ((c * H + h) * N) * D + d;
#pragma unroll
        for (int n = 0; n < N; ++n) Lp[n * D] = s[n];
        if (d == 0) Pbuf[h * NC + c] = P;
    }

    cg::this_grid().sync();

    // ---- Phase B: wave 0 of each block -> 16384 lanes, 1 wave/CU ----
    if (wv == 0) {
        const int idx = blockIdx.x * 64 + d;        // h*1024 + n*64 + d
        const int hh = idx >> 10;                   // wave-uniform
        float carry = ic[idx];
#pragma unroll
        for (int r = 0; r < NC / 64; ++r) {
            float l[64];
#pragma unroll
            for (int k = 0; k < 64; ++k)
                l[k] = Lbuf[(r * 64 + k) * (H * N * D) + idx];
#pragma unroll
            for (int k = 0; k < 64; ++k) {
                const float p = Pbuf[hh * NC + r * 64 + k];  // s_load
                Lbuf[(r * 64 + k) * (H * N * D) + idx] = carry;  // entry
                carry = p * carry + l[k];
            }
        }
        out[idx] = carry;                           // next_carry
    }

    cg::this_grid().sync();

    // ---- Phase C: entry correction, out = out_local + pa * (C . E) ----
    float E[N];
    {
        const float* Ep = Lbuf + ((c * H + h) * N) * D + d;
#pragma unroll
        for (int n = 0; n < N; ++n) E[n] = Ep[n * D];
    }
    float pa = 1.f;
    float* outp = out + H * N * D;
#pragma unroll
    for (int ss = 0; ss < CL; ++ss) {
        const float dtv = dt[(t0 + ss) * H + h];    // L2-resident s_load
        const float mv  = mask[t0 + ss];
        pa *= (1.f - mv) * __expf(dtv * rate);
        const float4* Cr4 = (const float4*)(Cs[wv] + ss * N);
        float corr = 0.f;
#pragma unroll
        for (int q = 0; q < 4; ++q) {
            const float4 cv = Cr4[q];
            corr += cv.x * E[4*q+0] + cv.y * E[4*q+1]
                  + cv.z * E[4*q+2] + cv.w * E[4*q+3];
        }
        outp[((t0 + ss) * H + h) * D + d] = Xs[wv][ss][d] + pa * corr;
    }
}

extern "C" void kernel_launch(void* const* d_in, const int* in_sizes, int n_in,
                              void* d_out, int out_size, void* d_ws, size_t ws_size,
                              hipStream_t stream) {
    const float* x    = (const float*)d_in[0];
    const float* dt   = (const float*)d_in[1];
    const float* B    = (const float*)d_in[2];
    const float* C    = (const float*)d_in[3];
    const float* mask = (const float*)d_in[4];
    const float* ic   = (const float*)d_in[5];
    const float* ld   = (const float*)d_in[6];
    const float* sw   = (const float*)d_in[7];
    float* out = (float*)d_out;

    float* Lbuf = (float*)d_ws;                      // NC*H*N*D floats
    float* Pbuf = Lbuf + (size_t)NC * H * N * D;     // H*NC floats

    void* args[] = {(void*)&x, (void*)&dt, (void*)&B, (void*)&C,
                    (void*)&mask, (void*)&ic, (void*)&ld, (void*)&sw,
                    (void*)&out, (void*)&Lbuf, (void*)&Pbuf};
    hipLaunchCooperativeKernel((void*)mamba_fused, dim3(NBLK), dim3(WPB * 64),
                               args, 0, stream);
}

// Round 9
// 41.089 us; speedup vs baseline: 11.4243x; 2.8024x over previous
//
#include <hip/hip_runtime.h>

#define T_LEN 4096
#define H 16
#define N 16
#define D 64
#define NC 128
#define CL (T_LEN / NC)   // 32

// 3-kernel chunked scan (cooperative fusion abandoned: 2 grid syncs cost
// ~80 us on 8 XCDs; kernel boundaries provide the same ordering cheaper).

// ---------------------------------------------------------------------------
// Phase 1: one wave per (chunk c, head h). Lane d owns the n-column (16 regs).
// B panel staged in LDS pre-scaled by dt; float4 broadcast reads in the scan.
// Writes L[c][h][n][d] (nontemporal) and P[h][c].
// ---------------------------------------------------------------------------
__global__ __launch_bounds__(64)
void phase1(const float* __restrict__ x, const float* __restrict__ dt,
            const float* __restrict__ B, const float* __restrict__ mask,
            const float* __restrict__ log_decay,
            float* __restrict__ Lbuf, float* __restrict__ Pbuf) {
    const int c = blockIdx.x, h = blockIdx.y;   // scalar -> s_load addressing
    const int d = threadIdx.x;
    const float rate = -__expf(log_decay[h]);
    const int t0 = c * CL;

    __shared__ float Bs[CL * N];                 // 2 KB, dt-scaled
    {
        const float4* Bg = (const float4*)B;
        float4* Bsv = (float4*)Bs;
#pragma unroll
        for (int i = 0; i < (CL * N / 4) / 64; ++i) {   // 2 iters
            const int j = i * 64 + d;
            const int row = j >> 2, off = j & 3;
            const float dtv = dt[(t0 + row) * H + h];
            float4 bv = Bg[((t0 + row) * H + h) * (N / 4) + off];
            bv.x *= dtv; bv.y *= dtv; bv.z *= dtv; bv.w *= dtv;
            Bsv[j] = bv;
        }
    }
    __syncthreads();

    float s[N];
#pragma unroll
    for (int n = 0; n < N; ++n) s[n] = 0.f;
    float P = 1.f;

#pragma unroll
    for (int ss = 0; ss < CL; ++ss) {
        const int t = t0 + ss;
        const float dtv = dt[t * H + h];          // s_load
        const float mv  = mask[t];                // s_load
        const float a   = (1.f - mv) * __expf(dtv * rate);
        const float xv  = x[(t * H + h) * D + d]; // per-lane coalesced
        P *= a;
        const float4* Br4 = (const float4*)(Bs + ss * N);
#pragma unroll
        for (int q = 0; q < 4; ++q) {             // ds_read_b128 broadcast
            const float4 bv = Br4[q];
            s[4*q+0] = a * s[4*q+0] + bv.x * xv;
            s[4*q+1] = a * s[4*q+1] + bv.y * xv;
            s[4*q+2] = a * s[4*q+2] + bv.z * xv;
            s[4*q+3] = a * s[4*q+3] + bv.w * xv;
        }
    }

    float* Lp = Lbuf + ((c * H + h) * N) * D + d;
#pragma unroll
    for (int n = 0; n < N; ++n)
        __builtin_nontemporal_store(s[n], Lp + n * D);   // streaming
    if (d == 0) Pbuf[h * NC + c] = P;             // [h][c]
}

// ---------------------------------------------------------------------------
// Phase 2: 16384 threads, one per (h,n,d). 64-deep prefetch -> 2 latency
// rounds. h block-uniform -> P reads are s_loads. Overwrites L in place
// with chunk ENTRY states; writes next_carry.
// ---------------------------------------------------------------------------
__global__ __launch_bounds__(256)
void phase2(const float* __restrict__ initial_carry,
            float* __restrict__ LE, const float* __restrict__ Pbuf,
            float* __restrict__ next_carry) {
    const int idx = blockIdx.x * 256 + threadIdx.x;  // h*1024 + n*64 + d
    const int h = blockIdx.x >> 2;                   // block-uniform
    float carry = initial_carry[idx];

#pragma unroll
    for (int r = 0; r < NC / 64; ++r) {              // 2 rounds
        float l[64];
#pragma unroll
        for (int k = 0; k < 64; ++k)
            l[k] = LE[(r * 64 + k) * (H * N * D) + idx];
#pragma unroll
        for (int k = 0; k < 64; ++k) {
            const float p = Pbuf[h * NC + r * 64 + k];   // s_load
            LE[(r * 64 + k) * (H * N * D) + idx] = carry;  // entry state
            carry = p * carry + l[k];
        }
    }
    next_carry[idx] = carry;
}

// ---------------------------------------------------------------------------
// Phase 3: re-scan each chunk from its entry state; fused C-projection
// (thread-local over n) + skip. B (dt-scaled) and C panels in LDS, float4
// broadcast reads. Nontemporal output stores.
// ---------------------------------------------------------------------------
__global__ __launch_bounds__(64)
void phase3(const float* __restrict__ x, const float* __restrict__ dt,
            const float* __restrict__ B, const float* __restrict__ C,
            const float* __restrict__ mask, const float* __restrict__ log_decay,
            const float* __restrict__ skip_weight,
            const float* __restrict__ Ebuf, float* __restrict__ out) {
    const int c = blockIdx.x, h = blockIdx.y;
    const int d = threadIdx.x;
    const float rate = -__expf(log_decay[h]);
    const int t0 = c * CL;

    __shared__ float Bs[CL * N], Cs[CL * N];         // 4 KB
    {
        const float4* Bg = (const float4*)B;
        const float4* Cg = (const float4*)C;
        float4* Bsv = (float4*)Bs;
        float4* Csv = (float4*)Cs;
#pragma unroll
        for (int i = 0; i < (CL * N / 4) / 64; ++i) {
            const int j = i * 64 + d;
            const int row = j >> 2, off = j & 3;
            const float dtv = dt[(t0 + row) * H + h];
            float4 bv = Bg[((t0 + row) * H + h) * (N / 4) + off];
            bv.x *= dtv; bv.y *= dtv; bv.z *= dtv; bv.w *= dtv;
            Bsv[j] = bv;
            Csv[j] = Cg[((t0 + row) * H + h) * (N / 4) + off];
        }
    }
    __syncthreads();

    float s[N];
    const float* Ep = Ebuf + ((c * H + h) * N) * D + d;
#pragma unroll
    for (int n = 0; n < N; ++n) s[n] = Ep[n * D];

    const float sw = skip_weight[h * D + d];
#pragma unroll
    for (int ss = 0; ss < CL; ++ss) {
        const int t = t0 + ss;
        const float dtv = dt[t * H + h];
        const float mv  = mask[t];
        const float a   = (1.f - mv) * __expf(dtv * rate);
        const float xv  = x[(t * H + h) * D + d];
        float acc = sw * xv;
        const float4* Br4 = (const float4*)(Bs + ss * N);
        const float4* Cr4 = (const float4*)(Cs + ss * N);
#pragma unroll
        for (int q = 0; q < 4; ++q) {
            const float4 bv = Br4[q];
            const float4 cv = Cr4[q];
            s[4*q+0] = a * s[4*q+0] + bv.x * xv;  acc += cv.x * s[4*q+0];
            s[4*q+1] = a * s[4*q+1] + bv.y * xv;  acc += cv.y * s[4*q+1];
            s[4*q+2] = a * s[4*q+2] + bv.z * xv;  acc += cv.z * s[4*q+2];
            s[4*q+3] = a * s[4*q+3] + bv.w * xv;  acc += cv.w * s[4*q+3];
        }
        __builtin_nontemporal_store(acc, &out[(t * H + h) * D + d]);
    }
}

extern "C" void kernel_launch(void* const* d_in, const int* in_sizes, int n_in,
                              void* d_out, int out_size, void* d_ws, size_t ws_size,
                              hipStream_t stream) {
    const float* x    = (const float*)d_in[0];
    const float* dt   = (const float*)d_in[1];
    const float* B    = (const float*)d_in[2];
    const float* C    = (const float*)d_in[3];
    const float* mask = (const float*)d_in[4];
    const float* ic   = (const float*)d_in[5];
    const float* ld   = (const float*)d_in[6];
    const float* sw   = (const float*)d_in[7];
    float* out = (float*)d_out;

    float* Lbuf = (float*)d_ws;                      // NC*H*N*D floats (8.4 MB)
    float* Pbuf = Lbuf + (size_t)NC * H * N * D;     // H*NC floats

    dim3 grid(NC, H), block(64);
    phase1<<<grid, block, 0, stream>>>(x, dt, B, mask, ld, Lbuf, Pbuf);
    phase2<<<dim3(H * N * D / 256), dim3(256), 0, stream>>>(ic, Lbuf, Pbuf, out);
    phase3<<<grid, block, 0, stream>>>(x, dt, B, C, mask, ld, sw, Lbuf, out + H * N * D);
}